// Round 5
// baseline (739.742 us; speedup 1.0000x reference)
//
#include <hip/hip_runtime.h>
#include <stdint.h>

#define N_NODES 100000
#define D 256
#define NT 4

typedef float f32x4 __attribute__((ext_vector_type(4)));
typedef __bf16 bf16x8 __attribute__((ext_vector_type(8)));

__device__ __forceinline__ unsigned short f2bf(float f) {
    unsigned u = __float_as_uint(f);
    u += 0x7FFF + ((u >> 16) & 1);        // round-to-nearest-even
    return (unsigned short)(u >> 16);
}

__device__ __forceinline__ void gload_lds16(const void* g, void* lds) {
    __builtin_amdgcn_global_load_lds(
        (const __attribute__((address_space(1))) unsigned int*)g,
        (__attribute__((address_space(3))) unsigned int*)lds, 16, 0, 0);
}

// ---------------- per-(type,dst) counting ----------------

template<int SHAPE>
__global__ void k_count(const int* __restrict__ idx, const int* __restrict__ etype,
                        int E, int* __restrict__ counts) {
    int e = blockIdx.x * 256 + threadIdx.x;
    if (e >= E) return;
    int t = etype[e];
    int dst = idx[(size_t)SHAPE * E + (size_t)SHAPE * e];
    atomicAdd(&counts[t * N_NODES + dst], 1);
}

// ---------------- exclusive scan over NT*N_NODES cells (3 kernels) ----------------

__global__ __launch_bounds__(256) void k_scan1(const int* __restrict__ in, int n,
        int* __restrict__ outv, int* __restrict__ bsums) {
    __shared__ int s[256];
    int tid = threadIdx.x;
    int i = blockIdx.x * 1024 + tid * 4;
    int v0 = 0, v1 = 0, v2 = 0, v3 = 0;
    if (i + 3 < n) {
        int4 v = *(const int4*)(in + i);
        v0 = v.x; v1 = v.y; v2 = v.z; v3 = v.w;
    } else {
        if (i     < n) v0 = in[i];
        if (i + 1 < n) v1 = in[i + 1];
        if (i + 2 < n) v2 = in[i + 2];
        if (i + 3 < n) v3 = in[i + 3];
    }
    int tsum = v0 + v1 + v2 + v3;
    s[tid] = tsum; __syncthreads();
    for (int off = 1; off < 256; off <<= 1) {
        int t = (tid >= off) ? s[tid - off] : 0;
        __syncthreads();
        s[tid] += t;
        __syncthreads();
    }
    int excl = s[tid] - tsum;
    if (tid == 255) bsums[blockIdx.x] = s[255];
    int o0 = excl, o1 = o0 + v0, o2 = o1 + v1, o3 = o2 + v2;
    if (i + 3 < n) {
        *(int4*)(outv + i) = make_int4(o0, o1, o2, o3);
    } else {
        if (i     < n) outv[i]     = o0;
        if (i + 1 < n) outv[i + 1] = o1;
        if (i + 2 < n) outv[i + 2] = o2;
        if (i + 3 < n) outv[i + 3] = o3;
    }
}

__global__ void k_scan2(int* __restrict__ bsums, int nb) {
    __shared__ int s[512];
    int t = threadIdx.x;
    int v = (t < nb) ? bsums[t] : 0;
    s[t] = v; __syncthreads();
    for (int off = 1; off < 512; off <<= 1) {
        int u = (t >= off) ? s[t - off] : 0;
        __syncthreads();
        s[t] += u;
        __syncthreads();
    }
    if (t < nb) bsums[t] = s[t] - v;   // exclusive
}

__global__ __launch_bounds__(256) void k_scan3(int* __restrict__ cellofs,
        int* __restrict__ cellcur, const int* __restrict__ bsums, int n) {
    int i = blockIdx.x * 1024 + threadIdx.x * 4;
    int add = bsums[blockIdx.x];
    if (i + 3 < n) {
        int4 v = *(int4*)(cellofs + i);
        v.x += add; v.y += add; v.z += add; v.w += add;
        *(int4*)(cellofs + i) = v;
        *(int4*)(cellcur + i) = v;
    } else {
        for (int k = 0; k < 4; ++k)
            if (i + k < n) { int v = cellofs[i + k] + add; cellofs[i + k] = v; cellcur[i + k] = v; }
    }
}

// ---------------- (type,dst)-sorted placement ----------------

template<int SHAPE>
__global__ void k_place(const int* __restrict__ idx, const int* __restrict__ etype, int E,
                        int* __restrict__ cellcur, int* __restrict__ bucket) {
    int e = blockIdx.x * 256 + threadIdx.x;
    if (e >= E) return;
    int t = etype[e];
    int dst = idx[(size_t)SHAPE * E + (size_t)SHAPE * e];
    int pos = atomicAdd(&cellcur[t * N_NODES + dst], 1);
    bucket[pos] = e;
}

// ---------------- f32 -> bf16 elementwise convert (x and W) ----------------

__global__ __launch_bounds__(256) void k_cvt(const float* __restrict__ in,
        unsigned short* __restrict__ ob, int n8) {
    int i = blockIdx.x * 256 + threadIdx.x;
    if (i >= n8) return;
    const float4* p = (const float4*)in + (size_t)i * 2;
    float4 v0 = p[0], v1 = p[1];
    union { unsigned short us[8]; uint4 u4; } o;
    o.us[0] = f2bf(v0.x); o.us[1] = f2bf(v0.y); o.us[2] = f2bf(v0.z); o.us[3] = f2bf(v0.w);
    o.us[4] = f2bf(v1.x); o.us[5] = f2bf(v1.y); o.us[6] = f2bf(v1.z); o.us[7] = f2bf(v1.w);
    *(uint4*)(ob + (size_t)i * 8) = o.u4;
}

// ---------------- A[t][K][D] -> AT[t][D][K] bf16 (transpose + convert) ----------------

__global__ void k_cvt_At(const float* __restrict__ A, unsigned short* __restrict__ AT, int K) {
    __shared__ float tl[32][33];
    const float* Ab = A + (size_t)blockIdx.z * K * D;
    unsigned short* Ob = AT + (size_t)blockIdx.z * D * K;
    int k0 = blockIdx.x * 32, j0 = blockIdx.y * 32;
    int lx = threadIdx.x, ly = threadIdx.y;   // 32 x 8
    for (int yy = ly; yy < 32; yy += 8)
        tl[yy][lx] = Ab[(size_t)(k0 + yy) * D + j0 + lx];
    __syncthreads();
    for (int yy = ly; yy < 32; yy += 8)
        Ob[(size_t)(j0 + yy) * K + k0 + lx] = f2bf(tl[lx][yy]);
}

// ---------------- dense: out = x @ W^T + b  (MFMA bf16) ----------------

__global__ __launch_bounds__(256) void k_init_mfma(const unsigned short* __restrict__ xb,
        const unsigned short* __restrict__ Wb, const float* __restrict__ bias,
        float* __restrict__ out, int n) {
    __shared__ __align__(16) char xs[64 * 128];
    int row0 = blockIdx.x * 64;
    int tid = threadIdx.x;
    int lane = tid & 63, w = tid >> 6;
    int l15 = lane & 15, l4 = lane >> 4;
    f32x4 acc[4][4];
    #pragma unroll
    for (int m = 0; m < 4; ++m)
        #pragma unroll
        for (int nn = 0; nn < 4; ++nn) acc[m][nn] = (f32x4)0.f;

    for (int kk = 0; kk < D; kk += 64) {
        #pragma unroll
        for (int it = 0; it < 2; ++it) {
            int f = it * 256 + tid;
            int r = f >> 3, q0 = f & 7;
            int q = q0 ^ (r & 7);
            int gr = row0 + r; if (gr >= n) gr = n - 1;
            gload_lds16(xb + (size_t)gr * D + kk + q * 8, xs + f * 16);
        }
        bf16x8 bfr[2][4];
        #pragma unroll
        for (int ks = 0; ks < 2; ++ks)
            #pragma unroll
            for (int nn = 0; nn < 4; ++nn) {
                int j = w * 64 + nn * 16 + l15;
                int k = kk + ks * 32 + l4 * 8;
                bfr[ks][nn] = *(const bf16x8*)(Wb + (size_t)j * D + k);
            }
        __syncthreads();
        #pragma unroll
        for (int ks = 0; ks < 2; ++ks)
            #pragma unroll
            for (int m = 0; m < 4; ++m) {
                int R = m * 16 + l15;
                int C = ks * 4 + l4;
                bf16x8 a = *(const bf16x8*)(xs + R * 128 + ((C ^ (R & 7)) << 4));
                #pragma unroll
                for (int nn = 0; nn < 4; ++nn)
                    acc[m][nn] = __builtin_amdgcn_mfma_f32_16x16x32_bf16(
                        a, bfr[ks][nn], acc[m][nn], 0, 0, 0);
            }
        __syncthreads();
    }
    #pragma unroll
    for (int m = 0; m < 4; ++m)
        #pragma unroll
        for (int nn = 0; nn < 4; ++nn) {
            int col = w * 64 + nn * 16 + l15;
            float bv = bias[col];
            #pragma unroll
            for (int r = 0; r < 4; ++r) {
                int row = row0 + m * 16 + l4 * 4 + r;
                if (row < n) out[(size_t)row * D + col] = acc[m][nn][r] + bv;
            }
        }
}

// ---------------- per-type gather-GEMM (MFMA, double-buffered) + atomic scatter ----------------
// 2-phase pipeline (T3 minimum form): per K-step issue B-frag loads FIRST, then
// next step's gather into xs[cur^1]; MFMA's bfr-wait is then vmcnt(2) (gathers
// may stay in flight); the single __syncthreads() per step drains the gather
// overlapped with the 32-MFMA cluster.

template<int SHAPE>
__global__ __launch_bounds__(256) void k_edge_mfma(const unsigned short* __restrict__ xb,
        const int* __restrict__ idx, const unsigned short* __restrict__ AT,
        float* __restrict__ out, int E,
        const int* __restrict__ counts, const int* __restrict__ cellofs,
        const int* __restrict__ bucket) {
    constexpr int K = SHAPE * 256;
    constexpr int NSTEP = K / 64;
    __shared__ __align__(16) char xs[2][64 * 128];
    __shared__ int srcS[SHAPE][64];
    __shared__ int dstS[64];
    __shared__ float normS[64];

    int t = blockIdx.y;
    int offs_t = cellofs[t * N_NODES];
    int end_t = (t == NT - 1) ? E : cellofs[(t + 1) * N_NODES];
    int cnt = end_t - offs_t;
    int tile = blockIdx.x * 64;
    if (tile >= cnt) return;
    int nE = min(64, cnt - tile);
    int base = offs_t + tile;
    int tid = threadIdx.x;

    if (tid < 64) {
        bool valid = tid < nE;
        int e = bucket[base + (valid ? tid : 0)];
        int dst = idx[(size_t)SHAPE * E + (size_t)SHAPE * e];
        dstS[tid] = dst;
        int c = counts[t * N_NODES + dst];
        normS[tid] = valid ? 1.0f / (float)(c > 1 ? c : 1) : 0.0f;
        srcS[0][tid] = idx[SHAPE * e];
        if (SHAPE == 2) srcS[SHAPE - 1][tid] = idx[SHAPE * e + SHAPE - 1];
    }
    __syncthreads();

    const unsigned short* Bt = AT + (size_t)t * D * K;
    int lane = tid & 63, w = tid >> 6;
    int l15 = lane & 15, l4 = lane >> 4;

    // per-thread staged gather coords (fixed across steps except node/col)
    int f0 = tid, f1 = 256 + tid;
    int r0s = f0 >> 3, q0s = (f0 & 7) ^ (r0s & 7);
    int r1s = f1 >> 3, q1s = (f1 & 7) ^ (r1s & 7);

    f32x4 acc[4][4];
    #pragma unroll
    for (int m = 0; m < 4; ++m)
        #pragma unroll
        for (int nn = 0; nn < 4; ++nn) acc[m][nn] = (f32x4)0.f;

    // prologue: stage step 0 into buf 0
    {
        int n0 = srcS[0][r0s], n1 = srcS[0][r1s];
        gload_lds16(xb + (size_t)n0 * D + q0s * 8, xs[0] + f0 * 16);
        gload_lds16(xb + (size_t)n1 * D + q1s * 8, xs[0] + f1 * 16);
    }
    __syncthreads();

    int cur = 0;
    #pragma unroll
    for (int st = 0; st < NSTEP; ++st) {
        int kk = st * 64;
        // (1) B-frag loads for this step (issued BEFORE next-step gathers)
        bf16x8 bfr[2][4];
        #pragma unroll
        for (int ks = 0; ks < 2; ++ks)
            #pragma unroll
            for (int nn = 0; nn < 4; ++nn) {
                int j = w * 64 + nn * 16 + l15;
                int k = kk + ks * 32 + l4 * 8;
                bfr[ks][nn] = *(const bf16x8*)(Bt + (size_t)j * K + k);
            }
        // (2) stage next K-step into the other buffer
        if (st + 1 < NSTEP) {
            int kn = kk + 64;
            int bank = (SHAPE == 2) ? (kn >> 8) : 0;
            int coln = kn & 255;
            int n0 = srcS[bank][r0s], n1 = srcS[bank][r1s];
            gload_lds16(xb + (size_t)n0 * D + coln + q0s * 8, xs[cur ^ 1] + f0 * 16);
            gload_lds16(xb + (size_t)n1 * D + coln + q1s * 8, xs[cur ^ 1] + f1 * 16);
        }
        // (3) MFMA on current buffer (bfr wait leaves gathers in flight)
        #pragma unroll
        for (int ks = 0; ks < 2; ++ks)
            #pragma unroll
            for (int m = 0; m < 4; ++m) {
                int R = m * 16 + l15;
                int C = ks * 4 + l4;
                bf16x8 a = *(const bf16x8*)(xs[cur] + R * 128 + ((C ^ (R & 7)) << 4));
                #pragma unroll
                for (int nn = 0; nn < 4; ++nn)
                    acc[m][nn] = __builtin_amdgcn_mfma_f32_16x16x32_bf16(
                        a, bfr[ks][nn], acc[m][nn], 0, 0, 0);
            }
        // (4) one drain+barrier per step: completes next-step gather
        __syncthreads();
        cur ^= 1;
    }

    // epilogue: normalized atomic scatter (dst-sorted -> L2-local)
    #pragma unroll
    for (int m = 0; m < 4; ++m)
        #pragma unroll
        for (int r = 0; r < 4; ++r) {
            int rr = m * 16 + l4 * 4 + r;
            if (rr < nE) {
                float nm = normS[rr];
                size_t ob = (size_t)dstS[rr] * D;
                #pragma unroll
                for (int nn = 0; nn < 4; ++nn) {
                    int col = w * 64 + nn * 16 + l15;
                    atomicAdd(&out[ob + col], nm * acc[m][nn][r]);
                }
            }
        }
}

// ---------------- launch ----------------

extern "C" void kernel_launch(void* const* d_in, const int* in_sizes, int n_in,
                              void* d_out, int out_size, void* d_ws, size_t ws_size,
                              hipStream_t stream) {
    const float* x  = (const float*)d_in[0];
    const int* idx1 = (const int*)d_in[1];
    const int* ty1  = (const int*)d_in[2];
    const int* idx2 = (const int*)d_in[3];
    const int* ty2  = (const int*)d_in[4];
    const float* A1 = (const float*)d_in[5];
    const float* A2 = (const float*)d_in[6];
    const float* W  = (const float*)d_in[7];
    const float* b  = (const float*)d_in[8];
    float* out = (float*)d_out;

    int E1 = in_sizes[2];
    int E2 = in_sizes[4];
    int maxE = E1 > E2 ? E1 : E2;
    const int NCELL = NT * N_NODES;
    const int NB = (NCELL + 1023) / 1024;

    char* p = (char*)d_ws;
    unsigned short* xb  = (unsigned short*)p; p += (size_t)N_NODES * D * 2;   // 51.2 MB
    unsigned short* Wb  = (unsigned short*)p; p += (size_t)D * D * 2;         // 128 KB
    unsigned short* A1T = (unsigned short*)p; p += (size_t)NT * D * 256 * 2;  // 512 KB
    unsigned short* A2T = (unsigned short*)p; p += (size_t)NT * D * 512 * 2;  // 1 MB
    int* counts  = (int*)p; p += (size_t)NCELL * 4;                           // 1.6 MB
    int* cellofs = (int*)p; p += (size_t)NCELL * 4;                           // 1.6 MB
    int* cellcur = (int*)p; p += (size_t)NCELL * 4;                           // 1.6 MB
    int* bsums   = (int*)p; p += 512 * 4;
    int* bucket  = (int*)p; p += (size_t)maxE * 4;                            // 1.2 MB

    // ---- prep: bf16 conversions / transposes ----
    k_cvt<<<(N_NODES * D / 8 + 255) / 256, 256, 0, stream>>>(x, xb, N_NODES * D / 8);
    k_cvt<<<(D * D / 8 + 255) / 256, 256, 0, stream>>>(W, Wb, D * D / 8);
    k_cvt_At<<<dim3(256 / 32, D / 32, NT), dim3(32, 8), 0, stream>>>(A1, A1T, 256);
    k_cvt_At<<<dim3(512 / 32, D / 32, NT), dim3(32, 8), 0, stream>>>(A2, A2T, 512);

    // ---- dense part ----
    k_init_mfma<<<(N_NODES + 63) / 64, 256, 0, stream>>>(xb, Wb, b, out, N_NODES);

    // ---- stage 1 (shape=1): count -> scan -> place((t,dst)-sorted) -> edge GEMM ----
    hipMemsetAsync(counts, 0, (size_t)NCELL * sizeof(int), stream);
    k_count<1><<<(E1 + 255) / 256, 256, 0, stream>>>(idx1, ty1, E1, counts);
    k_scan1<<<NB, 256, 0, stream>>>(counts, NCELL, cellofs, bsums);
    k_scan2<<<1, 512, 0, stream>>>(bsums, NB);
    k_scan3<<<NB, 256, 0, stream>>>(cellofs, cellcur, bsums, NCELL);
    k_place<1><<<(E1 + 255) / 256, 256, 0, stream>>>(idx1, ty1, E1, cellcur, bucket);
    k_edge_mfma<1><<<dim3((E1 + 63) / 64, NT), 256, 0, stream>>>(
        xb, idx1, A1T, out, E1, counts, cellofs, bucket);

    // ---- stage 2 (shape=2) ----
    hipMemsetAsync(counts, 0, (size_t)NCELL * sizeof(int), stream);
    k_count<2><<<(E2 + 255) / 256, 256, 0, stream>>>(idx2, ty2, E2, counts);
    k_scan1<<<NB, 256, 0, stream>>>(counts, NCELL, cellofs, bsums);
    k_scan2<<<1, 512, 0, stream>>>(bsums, NB);
    k_scan3<<<NB, 256, 0, stream>>>(cellofs, cellcur, bsums, NCELL);
    k_place<2><<<(E2 + 255) / 256, 256, 0, stream>>>(idx2, ty2, E2, cellcur, bucket);
    k_edge_mfma<2><<<dim3((E2 + 63) / 64, NT), 256, 0, stream>>>(
        xb, idx2, A2T, out, E2, counts, cellofs, bucket);
}

// Round 6
// 640.187 us; speedup vs baseline: 1.1555x; 1.1555x over previous
//
#include <hip/hip_runtime.h>
#include <stdint.h>

#define N_NODES 100000
#define D 256
#define NT 4

typedef float f32x4 __attribute__((ext_vector_type(4)));
typedef __bf16 bf16x8 __attribute__((ext_vector_type(8)));

__device__ __forceinline__ unsigned short f2bf(float f) {
    unsigned u = __float_as_uint(f);
    u += 0x7FFF + ((u >> 16) & 1);        // round-to-nearest-even
    return (unsigned short)(u >> 16);
}

__device__ __forceinline__ void gload_lds16(const void* g, void* lds) {
    __builtin_amdgcn_global_load_lds(
        (const __attribute__((address_space(1))) unsigned int*)g,
        (__attribute__((address_space(3))) unsigned int*)lds, 16, 0, 0);
}

// ---------------- per-(type,dst) counting ----------------

template<int SHAPE>
__global__ void k_count(const int* __restrict__ idx, const int* __restrict__ etype,
                        int E, int* __restrict__ counts) {
    int e = blockIdx.x * 256 + threadIdx.x;
    if (e >= E) return;
    int t = etype[e];
    int dst = idx[(size_t)SHAPE * E + (size_t)SHAPE * e];
    atomicAdd(&counts[t * N_NODES + dst], 1);
}

// ---------------- exclusive scan over NT*N_NODES cells (3 kernels) ----------------

__global__ __launch_bounds__(256) void k_scan1(const int* __restrict__ in, int n,
        int* __restrict__ outv, int* __restrict__ bsums) {
    __shared__ int s[256];
    int tid = threadIdx.x;
    int i = blockIdx.x * 1024 + tid * 4;
    int v0 = 0, v1 = 0, v2 = 0, v3 = 0;
    if (i + 3 < n) {
        int4 v = *(const int4*)(in + i);
        v0 = v.x; v1 = v.y; v2 = v.z; v3 = v.w;
    } else {
        if (i     < n) v0 = in[i];
        if (i + 1 < n) v1 = in[i + 1];
        if (i + 2 < n) v2 = in[i + 2];
        if (i + 3 < n) v3 = in[i + 3];
    }
    int tsum = v0 + v1 + v2 + v3;
    s[tid] = tsum; __syncthreads();
    for (int off = 1; off < 256; off <<= 1) {
        int t = (tid >= off) ? s[tid - off] : 0;
        __syncthreads();
        s[tid] += t;
        __syncthreads();
    }
    int excl = s[tid] - tsum;
    if (tid == 255) bsums[blockIdx.x] = s[255];
    int o0 = excl, o1 = o0 + v0, o2 = o1 + v1, o3 = o2 + v2;
    if (i + 3 < n) {
        *(int4*)(outv + i) = make_int4(o0, o1, o2, o3);
    } else {
        if (i     < n) outv[i]     = o0;
        if (i + 1 < n) outv[i + 1] = o1;
        if (i + 2 < n) outv[i + 2] = o2;
        if (i + 3 < n) outv[i + 3] = o3;
    }
}

__global__ void k_scan2(int* __restrict__ bsums, int nb) {
    __shared__ int s[512];
    int t = threadIdx.x;
    int v = (t < nb) ? bsums[t] : 0;
    s[t] = v; __syncthreads();
    for (int off = 1; off < 512; off <<= 1) {
        int u = (t >= off) ? s[t - off] : 0;
        __syncthreads();
        s[t] += u;
        __syncthreads();
    }
    if (t < nb) bsums[t] = s[t] - v;   // exclusive
}

__global__ __launch_bounds__(256) void k_scan3(int* __restrict__ cellofs,
        int* __restrict__ cellcur, const int* __restrict__ bsums, int n) {
    int i = blockIdx.x * 1024 + threadIdx.x * 4;
    int add = bsums[blockIdx.x];
    if (i + 3 < n) {
        int4 v = *(int4*)(cellofs + i);
        v.x += add; v.y += add; v.z += add; v.w += add;
        *(int4*)(cellofs + i) = v;
        *(int4*)(cellcur + i) = v;
    } else {
        for (int k = 0; k < 4; ++k)
            if (i + k < n) { int v = cellofs[i + k] + add; cellofs[i + k] = v; cellcur[i + k] = v; }
    }
}

// ---------------- (type,dst)-sorted placement ----------------

template<int SHAPE>
__global__ void k_place(const int* __restrict__ idx, const int* __restrict__ etype, int E,
                        int* __restrict__ cellcur, int* __restrict__ bucket) {
    int e = blockIdx.x * 256 + threadIdx.x;
    if (e >= E) return;
    int t = etype[e];
    int dst = idx[(size_t)SHAPE * E + (size_t)SHAPE * e];
    int pos = atomicAdd(&cellcur[t * N_NODES + dst], 1);
    bucket[pos] = e;
}

// ---------------- f32 -> bf16 elementwise convert (x and W) ----------------

__global__ __launch_bounds__(256) void k_cvt(const float* __restrict__ in,
        unsigned short* __restrict__ ob, int n8) {
    int i = blockIdx.x * 256 + threadIdx.x;
    if (i >= n8) return;
    const float4* p = (const float4*)in + (size_t)i * 2;
    float4 v0 = p[0], v1 = p[1];
    union { unsigned short us[8]; uint4 u4; } o;
    o.us[0] = f2bf(v0.x); o.us[1] = f2bf(v0.y); o.us[2] = f2bf(v0.z); o.us[3] = f2bf(v0.w);
    o.us[4] = f2bf(v1.x); o.us[5] = f2bf(v1.y); o.us[6] = f2bf(v1.z); o.us[7] = f2bf(v1.w);
    *(uint4*)(ob + (size_t)i * 8) = o.u4;
}

// ---------------- A[t][K][D] -> AT[t][D][K] bf16 (transpose + convert) ----------------

__global__ void k_cvt_At(const float* __restrict__ A, unsigned short* __restrict__ AT, int K) {
    __shared__ float tl[32][33];
    const float* Ab = A + (size_t)blockIdx.z * K * D;
    unsigned short* Ob = AT + (size_t)blockIdx.z * D * K;
    int k0 = blockIdx.x * 32, j0 = blockIdx.y * 32;
    int lx = threadIdx.x, ly = threadIdx.y;   // 32 x 8
    for (int yy = ly; yy < 32; yy += 8)
        tl[yy][lx] = Ab[(size_t)(k0 + yy) * D + j0 + lx];
    __syncthreads();
    for (int yy = ly; yy < 32; yy += 8)
        Ob[(size_t)(j0 + yy) * K + k0 + lx] = f2bf(tl[lx][yy]);
}

// ---------------- dense: out = x @ W^T + b  (MFMA bf16) ----------------

__global__ __launch_bounds__(256) void k_init_mfma(const unsigned short* __restrict__ xb,
        const unsigned short* __restrict__ Wb, const float* __restrict__ bias,
        float* __restrict__ out, int n) {
    __shared__ __align__(16) char xs[64 * 128];
    int row0 = blockIdx.x * 64;
    int tid = threadIdx.x;
    int lane = tid & 63, w = tid >> 6;
    int l15 = lane & 15, l4 = lane >> 4;
    f32x4 acc[4][4];
    #pragma unroll
    for (int m = 0; m < 4; ++m)
        #pragma unroll
        for (int nn = 0; nn < 4; ++nn) acc[m][nn] = (f32x4)0.f;

    for (int kk = 0; kk < D; kk += 64) {
        #pragma unroll
        for (int it = 0; it < 2; ++it) {
            int f = it * 256 + tid;
            int r = f >> 3, q0 = f & 7;
            int q = q0 ^ (r & 7);
            int gr = row0 + r; if (gr >= n) gr = n - 1;
            gload_lds16(xb + (size_t)gr * D + kk + q * 8, xs + f * 16);
        }
        bf16x8 bfr[2][4];
        #pragma unroll
        for (int ks = 0; ks < 2; ++ks)
            #pragma unroll
            for (int nn = 0; nn < 4; ++nn) {
                int j = w * 64 + nn * 16 + l15;
                int k = kk + ks * 32 + l4 * 8;
                bfr[ks][nn] = *(const bf16x8*)(Wb + (size_t)j * D + k);
            }
        __syncthreads();
        #pragma unroll
        for (int ks = 0; ks < 2; ++ks)
            #pragma unroll
            for (int m = 0; m < 4; ++m) {
                int R = m * 16 + l15;
                int C = ks * 4 + l4;
                bf16x8 a = *(const bf16x8*)(xs + R * 128 + ((C ^ (R & 7)) << 4));
                #pragma unroll
                for (int nn = 0; nn < 4; ++nn)
                    acc[m][nn] = __builtin_amdgcn_mfma_f32_16x16x32_bf16(
                        a, bfr[ks][nn], acc[m][nn], 0, 0, 0);
            }
        __syncthreads();
    }
    #pragma unroll
    for (int m = 0; m < 4; ++m)
        #pragma unroll
        for (int nn = 0; nn < 4; ++nn) {
            int col = w * 64 + nn * 16 + l15;
            float bv = bias[col];
            #pragma unroll
            for (int r = 0; r < 4; ++r) {
                int row = row0 + m * 16 + l4 * 4 + r;
                if (row < n) out[(size_t)row * D + col] = acc[m][nn][r] + bv;
            }
        }
}

// ---------------- per-type gather-GEMM (MFMA); epilogue: scratch-store OR atomic ----------------
// SCR=1: write normalized per-edge rows (bf16) to eo at the edge's sorted bucket
//        position -- coalesced 16B stores via LDS repack, ZERO atomics.
// SCR=0: fallback r4 atomic epilogue (used when ws_size is too small for eo).

template<int SHAPE, int SCR>
__global__ __launch_bounds__(256) void k_edge_mfma(const unsigned short* __restrict__ xb,
        const int* __restrict__ idx, const unsigned short* __restrict__ AT,
        float* __restrict__ out, unsigned short* __restrict__ eo, int E,
        const int* __restrict__ counts, const int* __restrict__ cellofs,
        const int* __restrict__ bucket) {
    constexpr int K = SHAPE * 256;
    __shared__ __align__(16) char xs[64 * 128];
    __shared__ int srcS[SHAPE][64];
    __shared__ int dstS[64];
    __shared__ float normS[64];

    int t = blockIdx.y;
    int offs_t = cellofs[t * N_NODES];
    int end_t = (t == NT - 1) ? E : cellofs[(t + 1) * N_NODES];
    int cnt = end_t - offs_t;
    int tile = blockIdx.x * 64;
    if (tile >= cnt) return;
    int nE = min(64, cnt - tile);
    int base = offs_t + tile;
    int tid = threadIdx.x;

    if (tid < 64) {
        bool valid = tid < nE;
        int e = bucket[base + (valid ? tid : 0)];
        int dst = idx[(size_t)SHAPE * E + (size_t)SHAPE * e];
        dstS[tid] = dst;
        int c = counts[t * N_NODES + dst];
        normS[tid] = valid ? 1.0f / (float)(c > 1 ? c : 1) : 0.0f;
        srcS[0][tid] = idx[SHAPE * e];
        if (SHAPE == 2) srcS[SHAPE - 1][tid] = idx[SHAPE * e + SHAPE - 1];
    }
    __syncthreads();

    const unsigned short* Bt = AT + (size_t)t * D * K;
    int lane = tid & 63, w = tid >> 6;
    int l15 = lane & 15, l4 = lane >> 4;
    f32x4 acc[4][4];
    #pragma unroll
    for (int m = 0; m < 4; ++m)
        #pragma unroll
        for (int nn = 0; nn < 4; ++nn) acc[m][nn] = (f32x4)0.f;

    for (int kk = 0; kk < K; kk += 64) {
        #pragma unroll
        for (int it = 0; it < 2; ++it) {
            int f = it * 256 + tid;
            int r = f >> 3, q0 = f & 7;
            int q = q0 ^ (r & 7);
            int node = srcS[SHAPE == 2 ? (kk >> 8) : 0][r];
            int col = (kk & 255) + q * 8;
            gload_lds16(xb + (size_t)node * D + col, xs + f * 16);
        }
        bf16x8 bfr[2][4];
        #pragma unroll
        for (int ks = 0; ks < 2; ++ks)
            #pragma unroll
            for (int nn = 0; nn < 4; ++nn) {
                int j = w * 64 + nn * 16 + l15;
                int k = kk + ks * 32 + l4 * 8;
                bfr[ks][nn] = *(const bf16x8*)(Bt + (size_t)j * K + k);
            }
        __syncthreads();
        #pragma unroll
        for (int ks = 0; ks < 2; ++ks)
            #pragma unroll
            for (int m = 0; m < 4; ++m) {
                int R = m * 16 + l15;
                int C = ks * 4 + l4;
                bf16x8 a = *(const bf16x8*)(xs + R * 128 + ((C ^ (R & 7)) << 4));
                #pragma unroll
                for (int nn = 0; nn < 4; ++nn)
                    acc[m][nn] = __builtin_amdgcn_mfma_f32_16x16x32_bf16(
                        a, bfr[ks][nn], acc[m][nn], 0, 0, 0);
            }
        __syncthreads();
    }

    if constexpr (SCR) {
        // repack normalized bf16 rows in LDS, then coalesced 16B stores
        __shared__ unsigned short re[64][264];
        #pragma unroll
        for (int m = 0; m < 4; ++m)
            #pragma unroll
            for (int r = 0; r < 4; ++r) {
                int rr = m * 16 + l4 * 4 + r;
                float nm = normS[rr];
                #pragma unroll
                for (int nn = 0; nn < 4; ++nn) {
                    int col = w * 64 + nn * 16 + l15;
                    re[rr][col] = f2bf(nm * acc[m][nn][r]);
                }
            }
        __syncthreads();
        #pragma unroll
        for (int it = 0; it < 8; ++it) {
            int f = it * 256 + tid;
            int row = f >> 5, seg = f & 31;
            if (row < nE) {
                uint4 v = *(const uint4*)&re[row][seg * 8];
                *(uint4*)(eo + (size_t)(base + row) * D + seg * 8) = v;
            }
        }
    } else {
        #pragma unroll
        for (int m = 0; m < 4; ++m)
            #pragma unroll
            for (int r = 0; r < 4; ++r) {
                int rr = m * 16 + l4 * 4 + r;
                if (rr < nE) {
                    float nm = normS[rr];
                    size_t ob = (size_t)dstS[rr] * D;
                    #pragma unroll
                    for (int nn = 0; nn < 4; ++nn) {
                        int col = w * 64 + nn * 16 + l15;
                        atomicAdd(&out[ob + col], nm * acc[m][nn][r]);
                    }
                }
            }
    }
}

// ---------------- dst-owned reduction: out[dst] += sum of scratch runs ----------------
// one wave per dst; lane owns 4 cols; runs are contiguous (edges (t,dst)-sorted)

__global__ __launch_bounds__(256) void k_reduce(const unsigned short* __restrict__ eo,
        const int* __restrict__ counts, const int* __restrict__ cellofs,
        float* __restrict__ out) {
    int wv = threadIdx.x >> 6, lane = threadIdx.x & 63;
    int dst = blockIdx.x * 4 + wv;
    if (dst >= N_NODES) return;
    float a0 = 0.f, a1 = 0.f, a2 = 0.f, a3 = 0.f;
    int tot = 0;
    #pragma unroll
    for (int t = 0; t < NT; ++t) {
        int start = cellofs[t * N_NODES + dst];
        int c = counts[t * N_NODES + dst];
        tot += c;
        for (int i = 0; i < c; ++i) {
            const unsigned short* row = eo + (size_t)(start + i) * D + lane * 4;
            uint2 v = *(const uint2*)row;
            a0 += __uint_as_float(v.x << 16);
            a1 += __uint_as_float(v.x & 0xFFFF0000u);
            a2 += __uint_as_float(v.y << 16);
            a3 += __uint_as_float(v.y & 0xFFFF0000u);
        }
    }
    if (tot) {
        float4* o = (float4*)&out[(size_t)dst * D + lane * 4];
        float4 cur = *o;
        cur.x += a0; cur.y += a1; cur.z += a2; cur.w += a3;
        *o = cur;
    }
}

// ---------------- launch ----------------

extern "C" void kernel_launch(void* const* d_in, const int* in_sizes, int n_in,
                              void* d_out, int out_size, void* d_ws, size_t ws_size,
                              hipStream_t stream) {
    const float* x  = (const float*)d_in[0];
    const int* idx1 = (const int*)d_in[1];
    const int* ty1  = (const int*)d_in[2];
    const int* idx2 = (const int*)d_in[3];
    const int* ty2  = (const int*)d_in[4];
    const float* A1 = (const float*)d_in[5];
    const float* A2 = (const float*)d_in[6];
    const float* W  = (const float*)d_in[7];
    const float* b  = (const float*)d_in[8];
    float* out = (float*)d_out;

    int E1 = in_sizes[2];
    int E2 = in_sizes[4];
    int maxE = E1 > E2 ? E1 : E2;
    const int NCELL = NT * N_NODES;
    const int NB = (NCELL + 1023) / 1024;
    const int NRB = (N_NODES + 3) / 4;

    char* p = (char*)d_ws;
    unsigned short* xb  = (unsigned short*)p; p += (size_t)N_NODES * D * 2;   // 51.2 MB
    unsigned short* Wb  = (unsigned short*)p; p += (size_t)D * D * 2;         // 128 KB
    unsigned short* A1T = (unsigned short*)p; p += (size_t)NT * D * 256 * 2;  // 512 KB
    unsigned short* A2T = (unsigned short*)p; p += (size_t)NT * D * 512 * 2;  // 1 MB
    int* counts  = (int*)p; p += (size_t)NCELL * 4;                           // 1.6 MB
    int* cellofs = (int*)p; p += (size_t)NCELL * 4;                           // 1.6 MB
    int* cellcur = (int*)p; p += (size_t)NCELL * 4;                           // 1.6 MB
    int* bsums   = (int*)p; p += 512 * 4;
    int* bucket  = (int*)p; p += (size_t)maxE * 4;                            // 1.2 MB
    unsigned short* eo = (unsigned short*)p; p += (size_t)maxE * D * 2;       // 153.6 MB
    bool scr = ((size_t)(p - (char*)d_ws)) <= ws_size;

    // ---- prep: bf16 conversions / transposes ----
    k_cvt<<<(N_NODES * D / 8 + 255) / 256, 256, 0, stream>>>(x, xb, N_NODES * D / 8);
    k_cvt<<<(D * D / 8 + 255) / 256, 256, 0, stream>>>(W, Wb, D * D / 8);
    k_cvt_At<<<dim3(256 / 32, D / 32, NT), dim3(32, 8), 0, stream>>>(A1, A1T, 256);
    k_cvt_At<<<dim3(512 / 32, D / 32, NT), dim3(32, 8), 0, stream>>>(A2, A2T, 512);

    // ---- dense part ----
    k_init_mfma<<<(N_NODES + 63) / 64, 256, 0, stream>>>(xb, Wb, b, out, N_NODES);

    // ---- stage 1 (shape=1): count -> scan -> place -> edge GEMM -> reduce ----
    hipMemsetAsync(counts, 0, (size_t)NCELL * sizeof(int), stream);
    k_count<1><<<(E1 + 255) / 256, 256, 0, stream>>>(idx1, ty1, E1, counts);
    k_scan1<<<NB, 256, 0, stream>>>(counts, NCELL, cellofs, bsums);
    k_scan2<<<1, 512, 0, stream>>>(bsums, NB);
    k_scan3<<<NB, 256, 0, stream>>>(cellofs, cellcur, bsums, NCELL);
    k_place<1><<<(E1 + 255) / 256, 256, 0, stream>>>(idx1, ty1, E1, cellcur, bucket);
    if (scr) {
        k_edge_mfma<1, 1><<<dim3((E1 + 63) / 64, NT), 256, 0, stream>>>(
            xb, idx1, A1T, out, eo, E1, counts, cellofs, bucket);
        k_reduce<<<NRB, 256, 0, stream>>>(eo, counts, cellofs, out);
    } else {
        k_edge_mfma<1, 0><<<dim3((E1 + 63) / 64, NT), 256, 0, stream>>>(
            xb, idx1, A1T, out, nullptr, E1, counts, cellofs, bucket);
    }

    // ---- stage 2 (shape=2) ----
    hipMemsetAsync(counts, 0, (size_t)NCELL * sizeof(int), stream);
    k_count<2><<<(E2 + 255) / 256, 256, 0, stream>>>(idx2, ty2, E2, counts);
    k_scan1<<<NB, 256, 0, stream>>>(counts, NCELL, cellofs, bsums);
    k_scan2<<<1, 512, 0, stream>>>(bsums, NB);
    k_scan3<<<NB, 256, 0, stream>>>(cellofs, cellcur, bsums, NCELL);
    k_place<2><<<(E2 + 255) / 256, 256, 0, stream>>>(idx2, ty2, E2, cellcur, bucket);
    if (scr) {
        k_edge_mfma<2, 1><<<dim3((E2 + 63) / 64, NT), 256, 0, stream>>>(
            xb, idx2, A2T, out, eo, E2, counts, cellofs, bucket);
        k_reduce<<<NRB, 256, 0, stream>>>(eo, counts, cellofs, out);
    } else {
        k_edge_mfma<2, 0><<<dim3((E2 + 63) / 64, NT), 256, 0, stream>>>(
            xb, idx2, A2T, out, nullptr, E2, counts, cellofs, bucket);
    }
}

// Round 8
// 607.741 us; speedup vs baseline: 1.2172x; 1.0534x over previous
//
#include <hip/hip_runtime.h>
#include <stdint.h>

#define N_NODES 100000
#define D 256
#define NT 4

typedef float f32x4 __attribute__((ext_vector_type(4)));
typedef __bf16 bf16x8 __attribute__((ext_vector_type(8)));
typedef unsigned int uint32x4 __attribute__((ext_vector_type(4)));
typedef unsigned int uint32x2 __attribute__((ext_vector_type(2)));

__device__ __forceinline__ unsigned short f2bf(float f) {
    unsigned u = __float_as_uint(f);
    u += 0x7FFF + ((u >> 16) & 1);        // round-to-nearest-even
    return (unsigned short)(u >> 16);
}

__device__ __forceinline__ void gload_lds16(const void* g, void* lds) {
    __builtin_amdgcn_global_load_lds(
        (const __attribute__((address_space(1))) unsigned int*)g,
        (__attribute__((address_space(3))) unsigned int*)lds, 16, 0, 0);
}

// ---------------- per-(type,dst) counting ----------------

template<int SHAPE>
__global__ void k_count(const int* __restrict__ idx, const int* __restrict__ etype,
                        int E, int* __restrict__ counts) {
    int e = blockIdx.x * 256 + threadIdx.x;
    if (e >= E) return;
    int t = etype[e];
    int dst = idx[(size_t)SHAPE * E + (size_t)SHAPE * e];
    atomicAdd(&counts[t * N_NODES + dst], 1);
}

// ---------------- exclusive scan over NT*N_NODES cells (3 kernels) ----------------

__global__ __launch_bounds__(256) void k_scan1(const int* __restrict__ in, int n,
        int* __restrict__ outv, int* __restrict__ bsums) {
    __shared__ int s[256];
    int tid = threadIdx.x;
    int i = blockIdx.x * 1024 + tid * 4;
    int v0 = 0, v1 = 0, v2 = 0, v3 = 0;
    if (i + 3 < n) {
        int4 v = *(const int4*)(in + i);
        v0 = v.x; v1 = v.y; v2 = v.z; v3 = v.w;
    } else {
        if (i     < n) v0 = in[i];
        if (i + 1 < n) v1 = in[i + 1];
        if (i + 2 < n) v2 = in[i + 2];
        if (i + 3 < n) v3 = in[i + 3];
    }
    int tsum = v0 + v1 + v2 + v3;
    s[tid] = tsum; __syncthreads();
    for (int off = 1; off < 256; off <<= 1) {
        int t = (tid >= off) ? s[tid - off] : 0;
        __syncthreads();
        s[tid] += t;
        __syncthreads();
    }
    int excl = s[tid] - tsum;
    if (tid == 255) bsums[blockIdx.x] = s[255];
    int o0 = excl, o1 = o0 + v0, o2 = o1 + v1, o3 = o2 + v2;
    if (i + 3 < n) {
        *(int4*)(outv + i) = make_int4(o0, o1, o2, o3);
    } else {
        if (i     < n) outv[i]     = o0;
        if (i + 1 < n) outv[i + 1] = o1;
        if (i + 2 < n) outv[i + 2] = o2;
        if (i + 3 < n) outv[i + 3] = o3;
    }
}

__global__ void k_scan2(int* __restrict__ bsums, int nb) {
    __shared__ int s[512];
    int t = threadIdx.x;
    int v = (t < nb) ? bsums[t] : 0;
    s[t] = v; __syncthreads();
    for (int off = 1; off < 512; off <<= 1) {
        int u = (t >= off) ? s[t - off] : 0;
        __syncthreads();
        s[t] += u;
        __syncthreads();
    }
    if (t < nb) bsums[t] = s[t] - v;   // exclusive
}

__global__ __launch_bounds__(256) void k_scan3(int* __restrict__ cellofs,
        int* __restrict__ cellcur, const int* __restrict__ bsums, int n) {
    int i = blockIdx.x * 1024 + threadIdx.x * 4;
    int add = bsums[blockIdx.x];
    if (i + 3 < n) {
        int4 v = *(int4*)(cellofs + i);
        v.x += add; v.y += add; v.z += add; v.w += add;
        *(int4*)(cellofs + i) = v;
        *(int4*)(cellcur + i) = v;
    } else {
        for (int k = 0; k < 4; ++k)
            if (i + k < n) { int v = cellofs[i + k] + add; cellofs[i + k] = v; cellcur[i + k] = v; }
    }
}

// ---------------- (type,dst)-sorted placement ----------------

template<int SHAPE>
__global__ void k_place(const int* __restrict__ idx, const int* __restrict__ etype, int E,
                        int* __restrict__ cellcur, int* __restrict__ bucket) {
    int e = blockIdx.x * 256 + threadIdx.x;
    if (e >= E) return;
    int t = etype[e];
    int dst = idx[(size_t)SHAPE * E + (size_t)SHAPE * e];
    int pos = atomicAdd(&cellcur[t * N_NODES + dst], 1);
    bucket[pos] = e;
}

// ---------------- f32 -> bf16 elementwise convert (x and W) ----------------

__global__ __launch_bounds__(256) void k_cvt(const float* __restrict__ in,
        unsigned short* __restrict__ ob, int n8) {
    int i = blockIdx.x * 256 + threadIdx.x;
    if (i >= n8) return;
    const float4* p = (const float4*)in + (size_t)i * 2;
    float4 v0 = p[0], v1 = p[1];
    union { unsigned short us[8]; uint4 u4; } o;
    o.us[0] = f2bf(v0.x); o.us[1] = f2bf(v0.y); o.us[2] = f2bf(v0.z); o.us[3] = f2bf(v0.w);
    o.us[4] = f2bf(v1.x); o.us[5] = f2bf(v1.y); o.us[6] = f2bf(v1.z); o.us[7] = f2bf(v1.w);
    *(uint4*)(ob + (size_t)i * 8) = o.u4;
}

// ---------------- A[t][K][D] -> AT[t][D][K] bf16 (transpose + convert) ----------------

__global__ void k_cvt_At(const float* __restrict__ A, unsigned short* __restrict__ AT, int K) {
    __shared__ float tl[32][33];
    const float* Ab = A + (size_t)blockIdx.z * K * D;
    unsigned short* Ob = AT + (size_t)blockIdx.z * D * K;
    int k0 = blockIdx.x * 32, j0 = blockIdx.y * 32;
    int lx = threadIdx.x, ly = threadIdx.y;   // 32 x 8
    for (int yy = ly; yy < 32; yy += 8)
        tl[yy][lx] = Ab[(size_t)(k0 + yy) * D + j0 + lx];
    __syncthreads();
    for (int yy = ly; yy < 32; yy += 8)
        Ob[(size_t)(j0 + yy) * K + k0 + lx] = f2bf(tl[lx][yy]);
}

// ---------------- dense: out = x @ W^T + b  (MFMA bf16) ----------------

__global__ __launch_bounds__(256) void k_init_mfma(const unsigned short* __restrict__ xb,
        const unsigned short* __restrict__ Wb, const float* __restrict__ bias,
        float* __restrict__ out, int n) {
    __shared__ __align__(16) char xs[64 * 128];
    int row0 = blockIdx.x * 64;
    int tid = threadIdx.x;
    int lane = tid & 63, w = tid >> 6;
    int l15 = lane & 15, l4 = lane >> 4;
    f32x4 acc[4][4];
    #pragma unroll
    for (int m = 0; m < 4; ++m)
        #pragma unroll
        for (int nn = 0; nn < 4; ++nn) acc[m][nn] = (f32x4)0.f;

    for (int kk = 0; kk < D; kk += 64) {
        #pragma unroll
        for (int it = 0; it < 2; ++it) {
            int f = it * 256 + tid;
            int r = f >> 3, q0 = f & 7;
            int q = q0 ^ (r & 7);
            int gr = row0 + r; if (gr >= n) gr = n - 1;
            gload_lds16(xb + (size_t)gr * D + kk + q * 8, xs + f * 16);
        }
        bf16x8 bfr[2][4];
        #pragma unroll
        for (int ks = 0; ks < 2; ++ks)
            #pragma unroll
            for (int nn = 0; nn < 4; ++nn) {
                int j = w * 64 + nn * 16 + l15;
                int k = kk + ks * 32 + l4 * 8;
                bfr[ks][nn] = *(const bf16x8*)(Wb + (size_t)j * D + k);
            }
        __syncthreads();
        #pragma unroll
        for (int ks = 0; ks < 2; ++ks)
            #pragma unroll
            for (int m = 0; m < 4; ++m) {
                int R = m * 16 + l15;
                int C = ks * 4 + l4;
                bf16x8 a = *(const bf16x8*)(xs + R * 128 + ((C ^ (R & 7)) << 4));
                #pragma unroll
                for (int nn = 0; nn < 4; ++nn)
                    acc[m][nn] = __builtin_amdgcn_mfma_f32_16x16x32_bf16(
                        a, bfr[ks][nn], acc[m][nn], 0, 0, 0);
            }
        __syncthreads();
    }
    #pragma unroll
    for (int m = 0; m < 4; ++m)
        #pragma unroll
        for (int nn = 0; nn < 4; ++nn) {
            int col = w * 64 + nn * 16 + l15;
            float bv = bias[col];
            #pragma unroll
            for (int r = 0; r < 4; ++r) {
                int row = row0 + m * 16 + l4 * 4 + r;
                if (row < n) out[(size_t)row * D + col] = acc[m][nn][r] + bv;
            }
        }
}

// ---------------- per-type gather-GEMM (MFMA); epilogue: nt scratch-store OR atomic ----------------
// SCR=1: repack in TWO 32-row halves (re[32][264] keeps LDS ~26KB -> 6 blocks/CU)
//        and write normalized bf16 rows with NON-TEMPORAL stores (keep xb in L3).

template<int SHAPE, int SCR>
__global__ __launch_bounds__(256) void k_edge_mfma(const unsigned short* __restrict__ xb,
        const int* __restrict__ idx, const unsigned short* __restrict__ AT,
        float* __restrict__ out, unsigned short* __restrict__ eo, int E,
        const int* __restrict__ counts, const int* __restrict__ cellofs,
        const int* __restrict__ bucket) {
    constexpr int K = SHAPE * 256;
    __shared__ __align__(16) char xs[64 * 128];
    __shared__ unsigned short re[32][264];   // half-tile repack buffer
    __shared__ int srcS[SHAPE][64];
    __shared__ int dstS[64];
    __shared__ float normS[64];

    int t = blockIdx.y;
    int offs_t = cellofs[t * N_NODES];
    int end_t = (t == NT - 1) ? E : cellofs[(t + 1) * N_NODES];
    int cnt = end_t - offs_t;
    int tile = blockIdx.x * 64;
    if (tile >= cnt) return;
    int nE = min(64, cnt - tile);
    int base = offs_t + tile;
    int tid = threadIdx.x;

    if (tid < 64) {
        bool valid = tid < nE;
        int e = bucket[base + (valid ? tid : 0)];
        int dst = idx[(size_t)SHAPE * E + (size_t)SHAPE * e];
        dstS[tid] = dst;
        int c = counts[t * N_NODES + dst];
        normS[tid] = valid ? 1.0f / (float)(c > 1 ? c : 1) : 0.0f;
        srcS[0][tid] = idx[SHAPE * e];
        if (SHAPE == 2) srcS[SHAPE - 1][tid] = idx[SHAPE * e + SHAPE - 1];
    }
    __syncthreads();

    const unsigned short* Bt = AT + (size_t)t * D * K;
    int lane = tid & 63, w = tid >> 6;
    int l15 = lane & 15, l4 = lane >> 4;
    f32x4 acc[4][4];
    #pragma unroll
    for (int m = 0; m < 4; ++m)
        #pragma unroll
        for (int nn = 0; nn < 4; ++nn) acc[m][nn] = (f32x4)0.f;

    for (int kk = 0; kk < K; kk += 64) {
        #pragma unroll
        for (int it = 0; it < 2; ++it) {
            int f = it * 256 + tid;
            int r = f >> 3, q0 = f & 7;
            int q = q0 ^ (r & 7);
            int node = srcS[SHAPE == 2 ? (kk >> 8) : 0][r];
            int col = (kk & 255) + q * 8;
            gload_lds16(xb + (size_t)node * D + col, xs + f * 16);
        }
        bf16x8 bfr[2][4];
        #pragma unroll
        for (int ks = 0; ks < 2; ++ks)
            #pragma unroll
            for (int nn = 0; nn < 4; ++nn) {
                int j = w * 64 + nn * 16 + l15;
                int k = kk + ks * 32 + l4 * 8;
                bfr[ks][nn] = *(const bf16x8*)(Bt + (size_t)j * K + k);
            }
        __syncthreads();
        #pragma unroll
        for (int ks = 0; ks < 2; ++ks)
            #pragma unroll
            for (int m = 0; m < 4; ++m) {
                int R = m * 16 + l15;
                int C = ks * 4 + l4;
                bf16x8 a = *(const bf16x8*)(xs + R * 128 + ((C ^ (R & 7)) << 4));
                #pragma unroll
                for (int nn = 0; nn < 4; ++nn)
                    acc[m][nn] = __builtin_amdgcn_mfma_f32_16x16x32_bf16(
                        a, bfr[ks][nn], acc[m][nn], 0, 0, 0);
            }
        __syncthreads();
    }

    if constexpr (SCR) {
        #pragma unroll
        for (int half = 0; half < 2; ++half) {
            if (half) __syncthreads();      // protect re reuse
            #pragma unroll
            for (int mi = 0; mi < 2; ++mi) {
                int m = half * 2 + mi;
                #pragma unroll
                for (int r = 0; r < 4; ++r) {
                    int rr = m * 16 + l4 * 4 + r;
                    float nm = normS[rr];
                    int rl = rr - half * 32;
                    #pragma unroll
                    for (int nn = 0; nn < 4; ++nn) {
                        int col = w * 64 + nn * 16 + l15;
                        re[rl][col] = f2bf(nm * acc[m][nn][r]);
                    }
                }
            }
            __syncthreads();
            #pragma unroll
            for (int it = 0; it < 4; ++it) {
                int f = it * 256 + tid;
                int row = f >> 5, seg = f & 31;
                int grow = half * 32 + row;
                if (grow < nE) {
                    uint32x4 v = *(const uint32x4*)&re[row][seg * 8];
                    __builtin_nontemporal_store(v,
                        (uint32x4*)(eo + (size_t)(base + grow) * D + seg * 8));
                }
            }
        }
    } else {
        #pragma unroll
        for (int m = 0; m < 4; ++m)
            #pragma unroll
            for (int r = 0; r < 4; ++r) {
                int rr = m * 16 + l4 * 4 + r;
                if (rr < nE) {
                    float nm = normS[rr];
                    size_t ob = (size_t)dstS[rr] * D;
                    #pragma unroll
                    for (int nn = 0; nn < 4; ++nn) {
                        int col = w * 64 + nn * 16 + l15;
                        atomicAdd(&out[ob + col], nm * acc[m][nn][r]);
                    }
                }
            }
    }
}

// ---------------- dst-owned reduction(s): out[dst] += sum of scratch runs ----------------

__device__ __forceinline__ void acc_runs(const unsigned short* __restrict__ eo,
        const int* __restrict__ counts, const int* __restrict__ cellofs,
        int dst, int lane, float& a0, float& a1, float& a2, float& a3, int& tot) {
    #pragma unroll
    for (int t = 0; t < NT; ++t) {
        int start = cellofs[t * N_NODES + dst];
        int c = counts[t * N_NODES + dst];
        tot += c;
        for (int i = 0; i < c; ++i) {
            const uint32x2* row = (const uint32x2*)(eo + (size_t)(start + i) * D + lane * 4);
            uint32x2 v = __builtin_nontemporal_load(row);
            a0 += __uint_as_float(v.x << 16);
            a1 += __uint_as_float(v.x & 0xFFFF0000u);
            a2 += __uint_as_float(v.y << 16);
            a3 += __uint_as_float(v.y & 0xFFFF0000u);
        }
    }
}

__global__ __launch_bounds__(256) void k_reduce_one(const unsigned short* __restrict__ eo,
        const int* __restrict__ counts, const int* __restrict__ cellofs,
        float* __restrict__ out) {
    int wv = threadIdx.x >> 6, lane = threadIdx.x & 63;
    int dst = blockIdx.x * 4 + wv;
    if (dst >= N_NODES) return;
    float a0 = 0.f, a1 = 0.f, a2 = 0.f, a3 = 0.f;
    int tot = 0;
    acc_runs(eo, counts, cellofs, dst, lane, a0, a1, a2, a3, tot);
    if (tot) {
        float4* o = (float4*)&out[(size_t)dst * D + lane * 4];
        float4 cur = *o;
        cur.x += a0; cur.y += a1; cur.z += a2; cur.w += a3;
        *o = cur;
    }
}

__global__ __launch_bounds__(256) void k_reduce_two(
        const unsigned short* __restrict__ eo1, const int* __restrict__ c1, const int* __restrict__ o1,
        const unsigned short* __restrict__ eo2, const int* __restrict__ c2, const int* __restrict__ o2,
        float* __restrict__ out) {
    int wv = threadIdx.x >> 6, lane = threadIdx.x & 63;
    int dst = blockIdx.x * 4 + wv;
    if (dst >= N_NODES) return;
    float a0 = 0.f, a1 = 0.f, a2 = 0.f, a3 = 0.f;
    int tot = 0;
    acc_runs(eo1, c1, o1, dst, lane, a0, a1, a2, a3, tot);
    acc_runs(eo2, c2, o2, dst, lane, a0, a1, a2, a3, tot);
    if (tot) {
        float4* o = (float4*)&out[(size_t)dst * D + lane * 4];
        float4 cur = *o;
        cur.x += a0; cur.y += a1; cur.z += a2; cur.w += a3;
        *o = cur;
    }
}

// ---------------- launch ----------------

extern "C" void kernel_launch(void* const* d_in, const int* in_sizes, int n_in,
                              void* d_out, int out_size, void* d_ws, size_t ws_size,
                              hipStream_t stream) {
    const float* x  = (const float*)d_in[0];
    const int* idx1 = (const int*)d_in[1];
    const int* ty1  = (const int*)d_in[2];
    const int* idx2 = (const int*)d_in[3];
    const int* ty2  = (const int*)d_in[4];
    const float* A1 = (const float*)d_in[5];
    const float* A2 = (const float*)d_in[6];
    const float* W  = (const float*)d_in[7];
    const float* b  = (const float*)d_in[8];
    float* out = (float*)d_out;

    int E1 = in_sizes[2];
    int E2 = in_sizes[4];
    int maxE = E1 > E2 ? E1 : E2;
    const int NCELL = NT * N_NODES;
    const int NB = (NCELL + 1023) / 1024;
    const int NRB = (N_NODES + 3) / 4;

    char* p = (char*)d_ws;
    unsigned short* xb  = (unsigned short*)p; p += (size_t)N_NODES * D * 2;   // 51.2 MB
    unsigned short* Wb  = (unsigned short*)p; p += (size_t)D * D * 2;
    unsigned short* A1T = (unsigned short*)p; p += (size_t)NT * D * 256 * 2;
    unsigned short* A2T = (unsigned short*)p; p += (size_t)NT * D * 512 * 2;
    int* counts1 = (int*)p; p += (size_t)NCELL * 4;
    int* cellofs1= (int*)p; p += (size_t)NCELL * 4;
    int* counts2 = (int*)p; p += (size_t)NCELL * 4;
    int* cellofs2= (int*)p; p += (size_t)NCELL * 4;
    int* cellcur = (int*)p; p += (size_t)NCELL * 4;
    int* bsums   = (int*)p; p += 512 * 4;
    int* bucket  = (int*)p; p += (size_t)maxE * 4;
    unsigned short* eo1 = (unsigned short*)p; p += (size_t)maxE * D * 2;      // 153.6 MB
    size_t need1 = (size_t)(p - (char*)d_ws);
    unsigned short* eo2 = (unsigned short*)p; p += (size_t)maxE * D * 2;      // 153.6 MB
    size_t need2 = (size_t)(p - (char*)d_ws);
    int mode = (need2 <= ws_size) ? 2 : (need1 <= ws_size) ? 1 : 0;

    // ---- prep: bf16 conversions / transposes ----
    k_cvt<<<(N_NODES * D / 8 + 255) / 256, 256, 0, stream>>>(x, xb, N_NODES * D / 8);
    k_cvt<<<(D * D / 8 + 255) / 256, 256, 0, stream>>>(W, Wb, D * D / 8);
    k_cvt_At<<<dim3(256 / 32, D / 32, NT), dim3(32, 8), 0, stream>>>(A1, A1T, 256);
    k_cvt_At<<<dim3(512 / 32, D / 32, NT), dim3(32, 8), 0, stream>>>(A2, A2T, 512);

    // ---- dense part ----
    k_init_mfma<<<(N_NODES + 63) / 64, 256, 0, stream>>>(xb, Wb, b, out, N_NODES);

    // ---- stage 1: count -> scan -> place -> edge GEMM ----
    hipMemsetAsync(counts1, 0, (size_t)NCELL * sizeof(int), stream);
    k_count<1><<<(E1 + 255) / 256, 256, 0, stream>>>(idx1, ty1, E1, counts1);
    k_scan1<<<NB, 256, 0, stream>>>(counts1, NCELL, cellofs1, bsums);
    k_scan2<<<1, 512, 0, stream>>>(bsums, NB);
    k_scan3<<<NB, 256, 0, stream>>>(cellofs1, cellcur, bsums, NCELL);
    k_place<1><<<(E1 + 255) / 256, 256, 0, stream>>>(idx1, ty1, E1, cellcur, bucket);
    if (mode) {
        k_edge_mfma<1, 1><<<dim3((E1 + 63) / 64, NT), 256, 0, stream>>>(
            xb, idx1, A1T, out, eo1, E1, counts1, cellofs1, bucket);
        if (mode == 1)
            k_reduce_one<<<NRB, 256, 0, stream>>>(eo1, counts1, cellofs1, out);
    } else {
        k_edge_mfma<1, 0><<<dim3((E1 + 63) / 64, NT), 256, 0, stream>>>(
            xb, idx1, A1T, out, nullptr, E1, counts1, cellofs1, bucket);
    }

    // ---- stage 2 ----
    hipMemsetAsync(counts2, 0, (size_t)NCELL * sizeof(int), stream);
    k_count<2><<<(E2 + 255) / 256, 256, 0, stream>>>(idx2, ty2, E2, counts2);
    k_scan1<<<NB, 256, 0, stream>>>(counts2, NCELL, cellofs2, bsums);
    k_scan2<<<1, 512, 0, stream>>>(bsums, NB);
    k_scan3<<<NB, 256, 0, stream>>>(cellofs2, cellcur, bsums, NCELL);
    k_place<2><<<(E2 + 255) / 256, 256, 0, stream>>>(idx2, ty2, E2, cellcur, bucket);
    if (mode) {
        unsigned short* eoS2 = (mode == 2) ? eo2 : eo1;
        k_edge_mfma<2, 1><<<dim3((E2 + 63) / 64, NT), 256, 0, stream>>>(
            xb, idx2, A2T, out, eoS2, E2, counts2, cellofs2, bucket);
        if (mode == 2)
            k_reduce_two<<<NRB, 256, 0, stream>>>(eo1, counts1, cellofs1,
                                                  eo2, counts2, cellofs2, out);
        else
            k_reduce_one<<<NRB, 256, 0, stream>>>(eo1, counts2, cellofs2, out);
    } else {
        k_edge_mfma<2, 0><<<dim3((E2 + 63) / 64, NT), 256, 0, stream>>>(
            xb, idx2, A2T, out, nullptr, E2, counts2, cellofs2, bucket);
    }
}

// Round 9
// 588.370 us; speedup vs baseline: 1.2573x; 1.0329x over previous
//
#include <hip/hip_runtime.h>
#include <stdint.h>

#define N_NODES 100000
#define D 256
#define NT 4

typedef float f32x4 __attribute__((ext_vector_type(4)));
typedef __bf16 bf16x8 __attribute__((ext_vector_type(8)));
typedef unsigned int uint32x4 __attribute__((ext_vector_type(4)));
typedef unsigned int uint32x2 __attribute__((ext_vector_type(2)));

__device__ __forceinline__ unsigned short f2bf(float f) {
    unsigned u = __float_as_uint(f);
    u += 0x7FFF + ((u >> 16) & 1);        // round-to-nearest-even
    return (unsigned short)(u >> 16);
}

__device__ __forceinline__ void gload_lds16(const void* g, void* lds) {
    __builtin_amdgcn_global_load_lds(
        (const __attribute__((address_space(1))) unsigned int*)g,
        (__attribute__((address_space(3))) unsigned int*)lds, 16, 0, 0);
}

// ---------------- per-(type,dst) counting ----------------

template<int SHAPE>
__global__ void k_count(const int* __restrict__ idx, const int* __restrict__ etype,
                        int E, int* __restrict__ counts) {
    int e = blockIdx.x * 256 + threadIdx.x;
    if (e >= E) return;
    int t = etype[e];
    int dst = idx[(size_t)SHAPE * E + (size_t)SHAPE * e];
    atomicAdd(&counts[t * N_NODES + dst], 1);
}

// ---------------- exclusive scan over NT*N_NODES cells (3 kernels) ----------------

__global__ __launch_bounds__(256) void k_scan1(const int* __restrict__ in, int n,
        int* __restrict__ outv, int* __restrict__ bsums) {
    __shared__ int s[256];
    int tid = threadIdx.x;
    int i = blockIdx.x * 1024 + tid * 4;
    int v0 = 0, v1 = 0, v2 = 0, v3 = 0;
    if (i + 3 < n) {
        int4 v = *(const int4*)(in + i);
        v0 = v.x; v1 = v.y; v2 = v.z; v3 = v.w;
    } else {
        if (i     < n) v0 = in[i];
        if (i + 1 < n) v1 = in[i + 1];
        if (i + 2 < n) v2 = in[i + 2];
        if (i + 3 < n) v3 = in[i + 3];
    }
    int tsum = v0 + v1 + v2 + v3;
    s[tid] = tsum; __syncthreads();
    for (int off = 1; off < 256; off <<= 1) {
        int t = (tid >= off) ? s[tid - off] : 0;
        __syncthreads();
        s[tid] += t;
        __syncthreads();
    }
    int excl = s[tid] - tsum;
    if (tid == 255) bsums[blockIdx.x] = s[255];
    int o0 = excl, o1 = o0 + v0, o2 = o1 + v1, o3 = o2 + v2;
    if (i + 3 < n) {
        *(int4*)(outv + i) = make_int4(o0, o1, o2, o3);
    } else {
        if (i     < n) outv[i]     = o0;
        if (i + 1 < n) outv[i + 1] = o1;
        if (i + 2 < n) outv[i + 2] = o2;
        if (i + 3 < n) outv[i + 3] = o3;
    }
}

__global__ void k_scan2(int* __restrict__ bsums, int nb) {
    __shared__ int s[512];
    int t = threadIdx.x;
    int v = (t < nb) ? bsums[t] : 0;
    s[t] = v; __syncthreads();
    for (int off = 1; off < 512; off <<= 1) {
        int u = (t >= off) ? s[t - off] : 0;
        __syncthreads();
        s[t] += u;
        __syncthreads();
    }
    if (t < nb) bsums[t] = s[t] - v;   // exclusive
}

__global__ __launch_bounds__(256) void k_scan3(int* __restrict__ cellofs,
        int* __restrict__ cellcur, const int* __restrict__ bsums, int n) {
    int i = blockIdx.x * 1024 + threadIdx.x * 4;
    int add = bsums[blockIdx.x];
    if (i + 3 < n) {
        int4 v = *(int4*)(cellofs + i);
        v.x += add; v.y += add; v.z += add; v.w += add;
        *(int4*)(cellofs + i) = v;
        *(int4*)(cellcur + i) = v;
    } else {
        for (int k = 0; k < 4; ++k)
            if (i + k < n) { int v = cellofs[i + k] + add; cellofs[i + k] = v; cellcur[i + k] = v; }
    }
}

// ---------------- (type,dst)-sorted placement ----------------

template<int SHAPE>
__global__ void k_place(const int* __restrict__ idx, const int* __restrict__ etype, int E,
                        int* __restrict__ cellcur, int* __restrict__ bucket) {
    int e = blockIdx.x * 256 + threadIdx.x;
    if (e >= E) return;
    int t = etype[e];
    int dst = idx[(size_t)SHAPE * E + (size_t)SHAPE * e];
    int pos = atomicAdd(&cellcur[t * N_NODES + dst], 1);
    bucket[pos] = e;
}

// ---------------- f32 -> bf16 elementwise convert (x and W) ----------------

__global__ __launch_bounds__(256) void k_cvt(const float* __restrict__ in,
        unsigned short* __restrict__ ob, int n8) {
    int i = blockIdx.x * 256 + threadIdx.x;
    if (i >= n8) return;
    const float4* p = (const float4*)in + (size_t)i * 2;
    float4 v0 = p[0], v1 = p[1];
    union { unsigned short us[8]; uint4 u4; } o;
    o.us[0] = f2bf(v0.x); o.us[1] = f2bf(v0.y); o.us[2] = f2bf(v0.z); o.us[3] = f2bf(v0.w);
    o.us[4] = f2bf(v1.x); o.us[5] = f2bf(v1.y); o.us[6] = f2bf(v1.z); o.us[7] = f2bf(v1.w);
    *(uint4*)(ob + (size_t)i * 8) = o.u4;
}

// ---------------- A[t][K][D] -> AT[t][D][K] bf16 (transpose + convert) ----------------

__global__ void k_cvt_At(const float* __restrict__ A, unsigned short* __restrict__ AT, int K) {
    __shared__ float tl[32][33];
    const float* Ab = A + (size_t)blockIdx.z * K * D;
    unsigned short* Ob = AT + (size_t)blockIdx.z * D * K;
    int k0 = blockIdx.x * 32, j0 = blockIdx.y * 32;
    int lx = threadIdx.x, ly = threadIdx.y;   // 32 x 8
    for (int yy = ly; yy < 32; yy += 8)
        tl[yy][lx] = Ab[(size_t)(k0 + yy) * D + j0 + lx];
    __syncthreads();
    for (int yy = ly; yy < 32; yy += 8)
        Ob[(size_t)(j0 + yy) * K + k0 + lx] = f2bf(tl[lx][yy]);
}

// ---------------- dense: out = x @ W^T + b  (MFMA bf16) ----------------

__global__ __launch_bounds__(256) void k_init_mfma(const unsigned short* __restrict__ xb,
        const unsigned short* __restrict__ Wb, const float* __restrict__ bias,
        float* __restrict__ out, int n) {
    __shared__ __align__(16) char xs[64 * 128];
    int row0 = blockIdx.x * 64;
    int tid = threadIdx.x;
    int lane = tid & 63, w = tid >> 6;
    int l15 = lane & 15, l4 = lane >> 4;
    f32x4 acc[4][4];
    #pragma unroll
    for (int m = 0; m < 4; ++m)
        #pragma unroll
        for (int nn = 0; nn < 4; ++nn) acc[m][nn] = (f32x4)0.f;

    for (int kk = 0; kk < D; kk += 64) {
        #pragma unroll
        for (int it = 0; it < 2; ++it) {
            int f = it * 256 + tid;
            int r = f >> 3, q0 = f & 7;
            int q = q0 ^ (r & 7);
            int gr = row0 + r; if (gr >= n) gr = n - 1;
            gload_lds16(xb + (size_t)gr * D + kk + q * 8, xs + f * 16);
        }
        bf16x8 bfr[2][4];
        #pragma unroll
        for (int ks = 0; ks < 2; ++ks)
            #pragma unroll
            for (int nn = 0; nn < 4; ++nn) {
                int j = w * 64 + nn * 16 + l15;
                int k = kk + ks * 32 + l4 * 8;
                bfr[ks][nn] = *(const bf16x8*)(Wb + (size_t)j * D + k);
            }
        __syncthreads();
        #pragma unroll
        for (int ks = 0; ks < 2; ++ks)
            #pragma unroll
            for (int m = 0; m < 4; ++m) {
                int R = m * 16 + l15;
                int C = ks * 4 + l4;
                bf16x8 a = *(const bf16x8*)(xs + R * 128 + ((C ^ (R & 7)) << 4));
                #pragma unroll
                for (int nn = 0; nn < 4; ++nn)
                    acc[m][nn] = __builtin_amdgcn_mfma_f32_16x16x32_bf16(
                        a, bfr[ks][nn], acc[m][nn], 0, 0, 0);
            }
        __syncthreads();
    }
    #pragma unroll
    for (int m = 0; m < 4; ++m)
        #pragma unroll
        for (int nn = 0; nn < 4; ++nn) {
            int col = w * 64 + nn * 16 + l15;
            float bv = bias[col];
            #pragma unroll
            for (int r = 0; r < 4; ++r) {
                int row = row0 + m * 16 + l4 * 4 + r;
                if (row < n) out[(size_t)row * D + col] = acc[m][nn][r] + bv;
            }
        }
}

// ---------------- per-type gather-GEMM (MFMA); epilogue: scratch-store OR atomic ----------------
// SCR=1: re[16][264] quarter-pass repack UNIONED with the xs staging buffer ->
//        total LDS ~9.5KB -> occupancy becomes VGPR-limited (5-6 blocks/CU).

template<int SHAPE, int SCR>
__global__ __launch_bounds__(256, 4) void k_edge_mfma(const unsigned short* __restrict__ xb,
        const int* __restrict__ idx, const unsigned short* __restrict__ AT,
        float* __restrict__ out, unsigned short* __restrict__ eo, int E,
        const int* __restrict__ counts, const int* __restrict__ cellofs,
        const int* __restrict__ bucket) {
    constexpr int K = SHAPE * 256;
    // union: K-loop staging xs (64*128=8192B) | epilogue repack re[16][264] (8448B)
    __shared__ __align__(16) char smem[16 * 264 * 2];
    __shared__ int srcS[SHAPE][64];
    __shared__ int dstS[64];
    __shared__ float normS[64];

    int t = blockIdx.y;
    int offs_t = cellofs[t * N_NODES];
    int end_t = (t == NT - 1) ? E : cellofs[(t + 1) * N_NODES];
    int cnt = end_t - offs_t;
    int tile = blockIdx.x * 64;
    if (tile >= cnt) return;
    int nE = min(64, cnt - tile);
    int base = offs_t + tile;
    int tid = threadIdx.x;

    if (tid < 64) {
        bool valid = tid < nE;
        int e = bucket[base + (valid ? tid : 0)];
        int dst = idx[(size_t)SHAPE * E + (size_t)SHAPE * e];
        dstS[tid] = dst;
        int c = counts[t * N_NODES + dst];
        normS[tid] = valid ? 1.0f / (float)(c > 1 ? c : 1) : 0.0f;
        srcS[0][tid] = idx[SHAPE * e];
        if (SHAPE == 2) srcS[SHAPE - 1][tid] = idx[SHAPE * e + SHAPE - 1];
    }
    __syncthreads();

    const unsigned short* Bt = AT + (size_t)t * D * K;
    int lane = tid & 63, w = tid >> 6;
    int l15 = lane & 15, l4 = lane >> 4;
    f32x4 acc[4][4];
    #pragma unroll
    for (int m = 0; m < 4; ++m)
        #pragma unroll
        for (int nn = 0; nn < 4; ++nn) acc[m][nn] = (f32x4)0.f;

    for (int kk = 0; kk < K; kk += 64) {
        #pragma unroll
        for (int it = 0; it < 2; ++it) {
            int f = it * 256 + tid;
            int r = f >> 3, q0 = f & 7;
            int q = q0 ^ (r & 7);
            int node = srcS[SHAPE == 2 ? (kk >> 8) : 0][r];
            int col = (kk & 255) + q * 8;
            gload_lds16(xb + (size_t)node * D + col, smem + f * 16);
        }
        bf16x8 bfr[2][4];
        #pragma unroll
        for (int ks = 0; ks < 2; ++ks)
            #pragma unroll
            for (int nn = 0; nn < 4; ++nn) {
                int j = w * 64 + nn * 16 + l15;
                int k = kk + ks * 32 + l4 * 8;
                bfr[ks][nn] = *(const bf16x8*)(Bt + (size_t)j * K + k);
            }
        __syncthreads();
        #pragma unroll
        for (int ks = 0; ks < 2; ++ks)
            #pragma unroll
            for (int m = 0; m < 4; ++m) {
                int R = m * 16 + l15;
                int C = ks * 4 + l4;
                bf16x8 a = *(const bf16x8*)(smem + R * 128 + ((C ^ (R & 7)) << 4));
                #pragma unroll
                for (int nn = 0; nn < 4; ++nn)
                    acc[m][nn] = __builtin_amdgcn_mfma_f32_16x16x32_bf16(
                        a, bfr[ks][nn], acc[m][nn], 0, 0, 0);
            }
        __syncthreads();
    }

    if constexpr (SCR) {
        unsigned short (*re)[264] = (unsigned short (*)[264])smem;
        #pragma unroll
        for (int q = 0; q < 4; ++q) {          // quarter q handles rows q*16..q*16+15
            if (q) __syncthreads();
            #pragma unroll
            for (int r = 0; r < 4; ++r) {
                int rl = l4 * 4 + r;
                float nm = normS[q * 16 + rl];
                #pragma unroll
                for (int nn = 0; nn < 4; ++nn) {
                    int col = w * 64 + nn * 16 + l15;
                    re[rl][col] = f2bf(nm * acc[q][nn][r]);
                }
            }
            __syncthreads();
            #pragma unroll
            for (int it = 0; it < 2; ++it) {
                int f = it * 256 + tid;
                int row = f >> 5, seg = f & 31;
                int grow = q * 16 + row;
                if (grow < nE) {
                    uint32x4 v = *(const uint32x4*)&re[row][seg * 8];
                    *(uint32x4*)(eo + (size_t)(base + grow) * D + seg * 8) = v;
                }
            }
        }
    } else {
        #pragma unroll
        for (int m = 0; m < 4; ++m)
            #pragma unroll
            for (int r = 0; r < 4; ++r) {
                int rr = m * 16 + l4 * 4 + r;
                if (rr < nE) {
                    float nm = normS[rr];
                    size_t ob = (size_t)dstS[rr] * D;
                    #pragma unroll
                    for (int nn = 0; nn < 4; ++nn) {
                        int col = w * 64 + nn * 16 + l15;
                        atomicAdd(&out[ob + col], nm * acc[m][nn][r]);
                    }
                }
            }
    }
}

// ---------------- dst-owned reduction(s): out[dst] += sum of scratch runs ----------------

__device__ __forceinline__ void acc_runs(const unsigned short* __restrict__ eo,
        const int* __restrict__ counts, const int* __restrict__ cellofs,
        int dst, int lane, float& a0, float& a1, float& a2, float& a3, int& tot) {
    #pragma unroll
    for (int t = 0; t < NT; ++t) {
        int start = cellofs[t * N_NODES + dst];
        int c = counts[t * N_NODES + dst];
        tot += c;
        for (int i = 0; i < c; ++i) {
            const uint32x2* row = (const uint32x2*)(eo + (size_t)(start + i) * D + lane * 4);
            uint32x2 v = __builtin_nontemporal_load(row);
            a0 += __uint_as_float(v.x << 16);
            a1 += __uint_as_float(v.x & 0xFFFF0000u);
            a2 += __uint_as_float(v.y << 16);
            a3 += __uint_as_float(v.y & 0xFFFF0000u);
        }
    }
}

__global__ __launch_bounds__(256) void k_reduce_one(const unsigned short* __restrict__ eo,
        const int* __restrict__ counts, const int* __restrict__ cellofs,
        float* __restrict__ out) {
    int wv = threadIdx.x >> 6, lane = threadIdx.x & 63;
    int dst = blockIdx.x * 4 + wv;
    if (dst >= N_NODES) return;
    float a0 = 0.f, a1 = 0.f, a2 = 0.f, a3 = 0.f;
    int tot = 0;
    acc_runs(eo, counts, cellofs, dst, lane, a0, a1, a2, a3, tot);
    if (tot) {
        float4* o = (float4*)&out[(size_t)dst * D + lane * 4];
        float4 cur = *o;
        cur.x += a0; cur.y += a1; cur.z += a2; cur.w += a3;
        *o = cur;
    }
}

__global__ __launch_bounds__(256) void k_reduce_two(
        const unsigned short* __restrict__ eo1, const int* __restrict__ c1, const int* __restrict__ o1,
        const unsigned short* __restrict__ eo2, const int* __restrict__ c2, const int* __restrict__ o2,
        float* __restrict__ out) {
    int wv = threadIdx.x >> 6, lane = threadIdx.x & 63;
    int dst = blockIdx.x * 4 + wv;
    if (dst >= N_NODES) return;
    float a0 = 0.f, a1 = 0.f, a2 = 0.f, a3 = 0.f;
    int tot = 0;
    acc_runs(eo1, c1, o1, dst, lane, a0, a1, a2, a3, tot);
    acc_runs(eo2, c2, o2, dst, lane, a0, a1, a2, a3, tot);
    if (tot) {
        float4* o = (float4*)&out[(size_t)dst * D + lane * 4];
        float4 cur = *o;
        cur.x += a0; cur.y += a1; cur.z += a2; cur.w += a3;
        *o = cur;
    }
}

// ---------------- launch ----------------

extern "C" void kernel_launch(void* const* d_in, const int* in_sizes, int n_in,
                              void* d_out, int out_size, void* d_ws, size_t ws_size,
                              hipStream_t stream) {
    const float* x  = (const float*)d_in[0];
    const int* idx1 = (const int*)d_in[1];
    const int* ty1  = (const int*)d_in[2];
    const int* idx2 = (const int*)d_in[3];
    const int* ty2  = (const int*)d_in[4];
    const float* A1 = (const float*)d_in[5];
    const float* A2 = (const float*)d_in[6];
    const float* W  = (const float*)d_in[7];
    const float* b  = (const float*)d_in[8];
    float* out = (float*)d_out;

    int E1 = in_sizes[2];
    int E2 = in_sizes[4];
    int maxE = E1 > E2 ? E1 : E2;
    const int NCELL = NT * N_NODES;
    const int NB = (NCELL + 1023) / 1024;
    const int NRB = (N_NODES + 3) / 4;

    char* p = (char*)d_ws;
    unsigned short* xb  = (unsigned short*)p; p += (size_t)N_NODES * D * 2;   // 51.2 MB
    unsigned short* Wb  = (unsigned short*)p; p += (size_t)D * D * 2;
    unsigned short* A1T = (unsigned short*)p; p += (size_t)NT * D * 256 * 2;
    unsigned short* A2T = (unsigned short*)p; p += (size_t)NT * D * 512 * 2;
    int* counts1 = (int*)p; p += (size_t)NCELL * 4;
    int* cellofs1= (int*)p; p += (size_t)NCELL * 4;
    int* counts2 = (int*)p; p += (size_t)NCELL * 4;
    int* cellofs2= (int*)p; p += (size_t)NCELL * 4;
    int* cellcur = (int*)p; p += (size_t)NCELL * 4;
    int* bsums   = (int*)p; p += 512 * 4;
    int* bucket  = (int*)p; p += (size_t)maxE * 4;
    unsigned short* eo1 = (unsigned short*)p; p += (size_t)maxE * D * 2;      // 153.6 MB
    size_t need1 = (size_t)(p - (char*)d_ws);
    unsigned short* eo2 = (unsigned short*)p; p += (size_t)maxE * D * 2;      // 153.6 MB
    size_t need2 = (size_t)(p - (char*)d_ws);
    int mode = (need2 <= ws_size) ? 2 : (need1 <= ws_size) ? 1 : 0;

    // ---- prep: bf16 conversions / transposes ----
    k_cvt<<<(N_NODES * D / 8 + 255) / 256, 256, 0, stream>>>(x, xb, N_NODES * D / 8);
    k_cvt<<<(D * D / 8 + 255) / 256, 256, 0, stream>>>(W, Wb, D * D / 8);
    k_cvt_At<<<dim3(256 / 32, D / 32, NT), dim3(32, 8), 0, stream>>>(A1, A1T, 256);
    k_cvt_At<<<dim3(512 / 32, D / 32, NT), dim3(32, 8), 0, stream>>>(A2, A2T, 512);

    // ---- dense part ----
    k_init_mfma<<<(N_NODES + 63) / 64, 256, 0, stream>>>(xb, Wb, b, out, N_NODES);

    // ---- stage 1: count -> scan -> place -> edge GEMM ----
    hipMemsetAsync(counts1, 0, (size_t)NCELL * sizeof(int), stream);
    k_count<1><<<(E1 + 255) / 256, 256, 0, stream>>>(idx1, ty1, E1, counts1);
    k_scan1<<<NB, 256, 0, stream>>>(counts1, NCELL, cellofs1, bsums);
    k_scan2<<<1, 512, 0, stream>>>(bsums, NB);
    k_scan3<<<NB, 256, 0, stream>>>(cellofs1, cellcur, bsums, NCELL);
    k_place<1><<<(E1 + 255) / 256, 256, 0, stream>>>(idx1, ty1, E1, cellcur, bucket);
    if (mode) {
        k_edge_mfma<1, 1><<<dim3((E1 + 63) / 64, NT), 256, 0, stream>>>(
            xb, idx1, A1T, out, eo1, E1, counts1, cellofs1, bucket);
        if (mode == 1)
            k_reduce_one<<<NRB, 256, 0, stream>>>(eo1, counts1, cellofs1, out);
    } else {
        k_edge_mfma<1, 0><<<dim3((E1 + 63) / 64, NT), 256, 0, stream>>>(
            xb, idx1, A1T, out, nullptr, E1, counts1, cellofs1, bucket);
    }

    // ---- stage 2 ----
    hipMemsetAsync(counts2, 0, (size_t)NCELL * sizeof(int), stream);
    k_count<2><<<(E2 + 255) / 256, 256, 0, stream>>>(idx2, ty2, E2, counts2);
    k_scan1<<<NB, 256, 0, stream>>>(counts2, NCELL, cellofs2, bsums);
    k_scan2<<<1, 512, 0, stream>>>(bsums, NB);
    k_scan3<<<NB, 256, 0, stream>>>(cellofs2, cellcur, bsums, NCELL);
    k_place<2><<<(E2 + 255) / 256, 256, 0, stream>>>(idx2, ty2, E2, cellcur, bucket);
    if (mode) {
        unsigned short* eoS2 = (mode == 2) ? eo2 : eo1;
        k_edge_mfma<2, 1><<<dim3((E2 + 63) / 64, NT), 256, 0, stream>>>(
            xb, idx2, A2T, out, eoS2, E2, counts2, cellofs2, bucket);
        if (mode == 2)
            k_reduce_two<<<NRB, 256, 0, stream>>>(eo1, counts1, cellofs1,
                                                  eo2, counts2, cellofs2, out);
        else
            k_reduce_one<<<NRB, 256, 0, stream>>>(eo1, counts2, cellofs2, out);
    } else {
        k_edge_mfma<2, 0><<<dim3((E2 + 63) / 64, NT), 256, 0, stream>>>(
            xb, idx2, A2T, out, nullptr, E2, counts2, cellofs2, bucket);
    }
}